// Round 12
// baseline (101.539 us; speedup 1.0000x reference)
//
#include <hip/hip_runtime.h>
#include <hip/hip_bf16.h>
#include <utility>

// out[131072,18] = theta(x)[131072,1330] @ (xi*mask)[1330,18]
// bf16 MFMA GEMM, round 18: PHASE-SPLIT BLOCKS at the 64-REG ALLOCATOR POINT.
// Order-4 symmetry rho = (0123)(4567)(89AB)(CDEF)(16 17): 1330 monomials ->
// 342 rep slots; per phase 43 chunks of (2 K-halves x 8 slots). Phase 0 uses
// rho-power g = h (h = lane>>5), phase 1 uses g = h+2.
// R11 calibration (vindy visible, clean): vindy = 43.5 us, VGPR=64, zero
// spill, ALL pipes <35% busy -> latency-bound at 16 waves/CU. R9 (4 blocks/
// CU, 55-58% occupancy) was ~33 us net of its spill traffic - occupancy DOES
// help; R9 failed only because launch_bounds(512,8) set the allocator budget
// to 32 regs. The untested combo = R9's structure + launch_bounds(512,4):
//  - (512,4) is the empirically unique spill-free 64-reg regime (6 expts);
//    the 2nd arg is an allocation MINIMUM, not an occupancy cap - HW runs
//    32 waves/CU at 64 VGPRs, so 4 blocks x 8 waves can be co-resident.
//  - block owns ONE phase for 256 rows: LDS 26144 B -> 4 blocks/CU = 32
//    waves/CU (HW max), grid 1024 = exactly 4/CU, zero tail.
//  - partials combine via unsafeAtomicAdd (global_atomic_add_f32) into a
//    memset-zeroed out; 2 commutative f32 adds/element = deterministic.
// Harness floor: unconditional 256 MiB poison fill (~43 us, partially
// overlapped) + aux/gaps + prep ~2 us.

constexpr int NVARS   = 18;
constexpr int NOUT    = 18;
constexpr int NROWS   = 131072;
constexpr int NCHUNKS = 43;             // chunks per phase
constexpr int NSLOTS  = NCHUNKS * 8;    // 344 (342 used + 2 pad)

constexpr int CH_STRIDE  = 304;                   // shorts per chunk: 2h x 19col x 8j
constexpr int PH_SHORTS  = NCHUNKS * CH_STRIDE;   // 13072 shorts = 26144 B per phase
constexpr int WF2_SHORTS = 2 * PH_SHORTS;         // full table (both phases)

typedef __attribute__((ext_vector_type(8)))  short short8;
typedef __attribute__((ext_vector_type(16))) float f32x16;

struct T3 { int a, b, c; };   // sorted ascending; 18 = unused factor; 19 = pad

constexpr int rho1(int v) {
    if (v < 16)  return (v & ~3) | ((v + 1) & 3);
    if (v == 16) return 17;
    if (v == 17) return 16;
    return v;
}
constexpr int rho2v(int v) { return rho1(rho1(v)); }

constexpr T3 sort3(int u0, int u1, int u2) {
    int t = 0;
    if (u0 > u1) { t = u0; u0 = u1; u1 = t; }
    if (u1 > u2) { t = u1; u1 = u2; u2 = t; }
    if (u0 > u1) { t = u0; u0 = u1; u1 = t; }
    return T3{u0, u1, u2};
}
constexpr T3 rho3(T3 t) { return sort3(rho1(t.a), rho1(t.b), rho1(t.c)); }

constexpr bool t3_less(T3 x, T3 y) {
    if (x.a != y.a) return x.a < y.a;
    if (x.b != y.b) return x.b < y.b;
    return x.c < y.c;
}
constexpr bool t3_eq(T3 x, T3 y) { return x.a == y.a && x.b == y.b && x.c == y.c; }

constexpr int rank_of(T3 t) {
    int deg = (t.a < 18) + (t.b < 18) + (t.c < 18);
    if (deg == 0) return 0;
    if (deg == 1) return 1 + t.a;
    if (deg == 2) {
        int r = 19;
        for (int a = 0; a < t.a; ++a) r += 18 - a;
        return r + (t.b - t.a);
    }
    int r = 190;
    for (int a = 0; a < t.a; ++a) { int n = 18 - a; r += n * (n + 1) / 2; }
    for (int b = t.a; b < t.b; ++b) r += 18 - b;
    return r + (t.c - t.b);
}

struct RepTables {
    signed char va[NSLOTS], vb[NSLOTS], vc[NSLOTS];
    short p[4][NSLOTS];   // flat term index for group g's k-position; -1 => zero W
    int count;
};

constexpr void consider(RepTables& R, int& s, T3 t) {
    T3 im[4] = {t, T3{0, 0, 0}, T3{0, 0, 0}, T3{0, 0, 0}};
    im[1] = rho3(im[0]);
    im[2] = rho3(im[1]);
    im[3] = rho3(im[2]);
    for (int g = 1; g < 4; ++g)
        if (t3_less(im[g], t)) return;   // not the orbit representative
    R.va[s] = (signed char)t.a; R.vb[s] = (signed char)t.b; R.vc[s] = (signed char)t.c;
    for (int g = 0; g < 4; ++g) {
        bool dup = false;
        for (int h = 0; h < g; ++h)
            if (t3_eq(im[h], im[g])) dup = true;
        R.p[g][s] = dup ? (short)-1 : (short)rank_of(im[g]);
    }
    ++s;
}

constexpr RepTables make_tables() {
    RepTables R{};
    int s = 0;
    consider(R, s, T3{18, 18, 18});
    for (int a = 0; a < NVARS; ++a) consider(R, s, T3{a, 18, 18});
    for (int a = 0; a < NVARS; ++a)
        for (int b = a; b < NVARS; ++b) consider(R, s, T3{a, b, 18});
    for (int a = 0; a < NVARS; ++a)
        for (int b = a; b < NVARS; ++b)
            for (int c = b; c < NVARS; ++c) consider(R, s, T3{a, b, c});
    R.count = s;
    for (; s < NSLOTS; ++s) {
        R.va[s] = 19; R.vb[s] = 19; R.vc[s] = 19;
        for (int g = 0; g < 4; ++g) R.p[g][s] = -1;
    }
    return R;
}

constexpr RepTables h_tab = make_tables();          // compile-time use
static_assert(h_tab.count == 342, "orbit enumeration must give 342 rep slots");
__device__ const RepTables d_tab = make_tables();   // runtime use (prep)

// Module-scope staging buffer for the prepped W table (NOT harness workspace).
__device__ __align__(16) short g_wf2[WF2_SHORTS];

// ---- bf16 pair pack --------------------------------------------------------

#if __has_builtin(__builtin_amdgcn_cvt_pk_bf16_f32)
typedef __bf16 bf16x2 __attribute__((ext_vector_type(2)));
__device__ __forceinline__ unsigned pack2(float f0, float f1) {
    bf16x2 r = __builtin_amdgcn_cvt_pk_bf16_f32(f0, f1);   // lo=f0, hi=f1, RNE
    return __builtin_bit_cast(unsigned, r);
}
#else
__device__ __forceinline__ unsigned pack2(float f0, float f1) {
    unsigned u0 = __float_as_uint(f0) + 0x8000u;
    unsigned u1 = __float_as_uint(f1) + 0x8000u;
    return __builtin_amdgcn_perm(u1, u0, 0x07060302u);     // lo=bf16(f0), hi=bf16(f1)
}
#endif

// ---- main kernel -----------------------------------------------------------

template <int S>
__device__ __forceinline__ float term_val(const float (&x)[NVARS]) {
    constexpr int a = h_tab.va[S], b = h_tab.vb[S], c = h_tab.vc[S];
    if constexpr (a >= 19)      return 0.0f;                 // pad slot
    else if constexpr (a == 18) return 1.0f;                 // constant
    else if constexpr (b == 18) return x[a];
    else if constexpr (c == 18) return x[a] * x[b];
    else                        return x[a] * x[b] * x[c];
}

union AFrag { unsigned u[4]; short8 v; };

// Fused eval+pack: keeps only 2 term floats live at a time.
template <int S, int... J>
__device__ __forceinline__ void pack8(const float (&x)[NVARS], AFrag& af,
                                      std::integer_sequence<int, J...>) {
    ((af.u[J] = pack2(term_val<S + 2 * J>(x), term_val<S + 2 * J + 1>(x))), ...);
}

// One chunk: slots CI*8..CI*8+7 (same slot indices for both phases; the
// phase picked which table half was staged into LDS).
template <int CI>
__device__ __forceinline__ void kstep32(const float (&x)[NVARS],
                                        const short* pB, f32x16& acc) {
    AFrag af;
    pack8<CI * 8>(x, af, std::make_integer_sequence<int, 4>{});
    short8 b = *(const short8*)(pB + CI * CH_STRIDE);   // ds_read_b128, imm offset
    acc = __builtin_amdgcn_mfma_f32_32x32x16_bf16(af.v, b, acc, 0, 0, 0);
}

template <int... CI>
__device__ __forceinline__ void kloop32(const float (&x)[NVARS],
                                        const short* pB, f32x16& acc,
                                        std::integer_sequence<int, CI...>) {
    (kstep32<CI>(x, pB, acc), ...);
}

__device__ __forceinline__ void load_x(const float* __restrict__ z,
                                       const float* __restrict__ betas,
                                       int arow, bool s1, bool s2, float (&x)[NVARS]) {
    float x0[NVARS];
    const float4* z4 = (const float4*)(z + (size_t)arow * 16);
    float4 v0 = z4[0], v1 = z4[1], v2 = z4[2], v3 = z4[3];
    x0[0]  = v0.x; x0[1]  = v0.y; x0[2]  = v0.z; x0[3]  = v0.w;
    x0[4]  = v1.x; x0[5]  = v1.y; x0[6]  = v1.z; x0[7]  = v1.w;
    x0[8]  = v2.x; x0[9]  = v2.y; x0[10] = v2.z; x0[11] = v2.w;
    x0[12] = v3.x; x0[13] = v3.y; x0[14] = v3.z; x0[15] = v3.w;
    const float2 b2 = *(const float2*)(betas + (size_t)arow * 2);
    x0[16] = b2.x; x0[17] = b2.y;
    float y[NVARS];
#pragma unroll
    for (int v = 0; v < NVARS; ++v) y[v] = s1 ? x0[rho1(v)] : x0[v];
#pragma unroll
    for (int v = 0; v < NVARS; ++v) x[v] = s2 ? y[rho2v(v)] : y[v];
}

__global__ __launch_bounds__(512, 4) void vindy_mfma(const float* __restrict__ z,
                                                     const float* __restrict__ betas,
                                                     float* __restrict__ out) {
    // One phase's table half: 26144 B -> 4 blocks/CU fit; launch_bounds(512,4)
    // keeps the allocator at the proven spill-free 64-reg point (min-waves is
    // an allocation GUARANTEE, not an occupancy cap -> HW can still run
    // 32 waves/CU at 64 VGPRs).
    __shared__ __align__(16) short ldsW[PH_SHORTS];

    const int phase = blockIdx.x & 1;          // adjacent blocks share rows -> L2-friendly
    const int row0b = (blockIdx.x >> 1) * 256;

    // stage this phase's W fragments (flat 16B copies, fully coalesced, L2-hot)
    {
        const float4* src = (const float4*)(g_wf2 + phase * PH_SHORTS);
        float4* dst = (float4*)ldsW;
        for (int i = threadIdx.x; i < PH_SHORTS / 8; i += 512) dst[i] = src[i];
    }
    __syncthreads();

    const int lane = threadIdx.x & 63;
    const int wave = threadIdx.x >> 6;   // 0..7
    const int h    = lane >> 5;          // K-half
    const int col  = lane & 31;          // A row within tile; C col
    const int row0 = row0b + wave * 32;

    // x permuted by rho^g, g = h + 2*phase
    const int g = h + 2 * phase;
    float x[NVARS];
    load_x(z, betas, row0 + col, (g & 1) != 0, (g & 2) != 0, x);

    const int col_eff = (col < NOUT) ? col : NOUT;   // col 18 = zero slot
    const short* pB = ldsW + h * 152 + col_eff * 8;

    f32x16 acc;
#pragma unroll
    for (int i = 0; i < 16; ++i) acc[i] = 0.0f;

    kloop32(x, pB, acc, std::make_integer_sequence<int, NCHUNKS>{});

    // C/D 32x32 layout: col = lane&31, row = (reg&3) + 8*(reg>>2) + 4*h.
    // Both phase blocks add their partial into the zeroed out buffer.
    // f32 add is commutative -> result is bit-deterministic for 2 addends.
    if (col < NOUT) {
        float* obase = out + (size_t)row0 * NOUT + col;
#pragma unroll
        for (int q = 0; q < 4; ++q) {
#pragma unroll
            for (int r = 0; r < 4; ++r) {
                int row = r + 8 * q + 4 * h;
#if defined(__HIP_DEVICE_COMPILE__)
                unsafeAtomicAdd(obase + (size_t)row * NOUT, acc[q * 4 + r]);  // global_atomic_add_f32
#else
                atomicAdd(obase + (size_t)row * NOUT, acc[q * 4 + r]);
#endif
            }
        }
    }
}

// ---- prep: W fragments in staged layout ------------------------------------
// g_wf2[c*304 + h*152 + col*8 + j]:
//   col < 18:  W[p[g][s]][col],  g = (c<43 ? h : 2+h),  s = (c<43 ? c : c-43)*8+j
//   col == 18: zero slot (read broadcast by lanes col>=18)

__global__ void prep_wfrag(const float* __restrict__ xi, const float* __restrict__ mask) {
    int i = blockIdx.x * blockDim.x + threadIdx.x;
    if (i >= WF2_SHORTS) return;
    int c  = i / CH_STRIDE;
    int r  = i - c * CH_STRIDE;
    int h  = r / 152;
    int r2 = r - h * 152;
    int col = r2 >> 3, j = r2 & 7;
    float v = 0.0f;
    if (col < NOUT) {
        int g = (c < 43 ? 0 : 2) + h;
        int s = (c < 43 ? c : c - 43) * 8 + j;
        int p = d_tab.p[g][s];
        if (p >= 0) v = xi[p * NOUT + col] * mask[p * NOUT + col];
    }
    g_wf2[i] = __builtin_bit_cast(short, __float2bfloat16(v));
}

extern "C" void kernel_launch(void* const* d_in, const int* in_sizes, int n_in,
                              void* d_out, int out_size, void* d_ws, size_t ws_size,
                              hipStream_t stream) {
    const float* z     = (const float*)d_in[0];
    const float* betas = (const float*)d_in[1];
    const float* xi    = (const float*)d_in[2];
    const float* mask  = (const float*)d_in[3];
    float* out = (float*)d_out;
    (void)d_ws; (void)ws_size;   // workspace unused (poison fill is unconditional anyway)

    hipMemsetAsync(out, 0, (size_t)out_size, stream);   // atomic accumulation base
    prep_wfrag<<<(WF2_SHORTS + 255) / 256, 256, 0, stream>>>(xi, mask);
    vindy_mfma<<<NROWS / 128, 512, 0, stream>>>(z, betas, out);   // 1024 blocks (2 phases x 512)
}

// Round 13
// 85.847 us; speedup vs baseline: 1.1828x; 1.1828x over previous
//
#include <hip/hip_runtime.h>
#include <hip/hip_bf16.h>
#include <utility>

// out[131072,18] = theta(x)[131072,1330] @ (xi*mask)[1330,18]
// bf16 MFMA GEMM — FINAL (verbatim best-of-session: R7 structure, benched
// 86.0 us (round 7) and 86.9 us (round 11)).
// Order-4 symmetry rho = (0123)(4567)(89AB)(CDEF)(16 17): 1330 monomials ->
// 342 rep slots. 32x32 A-layout has 2 K-halves per wave (h = lane>>5,
// k = h*8+j); one wave covers 32 rows; the 4 rho-powers are covered by two
// 43-chunk phases: chunks 0..42 use g = h, chunks 43..85 use g = h+2; the
// phase switch x2[v] = x1[rho2(v)] is a compile-time register renaming.
//
// Session ledger (13 experiments, why this exact shape is final):
//  - 512-thr blocks + launch_bounds(512,4) is the ONLY allocator regime that
//    yields a spill-free 64-VGPR body (others: (512,8)/(1024,8) -> 32 regs +
//    spill; bare 512 -> 64 + spill for 2-tile bodies; waves_per_eu ignored;
//    runtime loop -> scratch thrash).
//  - 32x32x16 MFMA halves ds_reads vs 16x16 (+3.3 us).
//  - Occupancy is NOT the limiter: 3 independent attempts (R8, R9, R12 -
//    the last spill-free on the fastest silicon) all null or negative.
//  - In-wave dual-chain ILP: null (R10).
//  - R11 clean capture: vindy = 43.5 us, VGPR 64, FETCH 5.2 MB / WRITE
//    10.2 MB (output only), VALUBusy 31%, MfmaUtil 8.7%, bank-conflict 2.6%
//    of cycles -> latency/issue-bound with no remaining source-level handle.
//  - Workspace must stay UNUSED (module-scope g_wf2 instead): the harness's
//    256 MiB poison fill (~41-44 us @ ~80% HBM peak) is unconditional and,
//    with aux/gaps, forms the ~43 us floor under dur_us ~= 86.

constexpr int NVARS   = 18;
constexpr int NOUT    = 18;
constexpr int NROWS   = 131072;
constexpr int NCHUNKS = 43;             // flat K = 43*32 = 1376 (4 g x 8 slots)
constexpr int NSLOTS  = NCHUNKS * 8;    // 344 (342 used + 2 pad)

constexpr int CH_STRIDE = 304;                    // shorts per chunk: 2h x 19col x 8j
constexpr int WF2_SHORTS = 86 * CH_STRIDE;        // 26144 shorts = 52288 B
constexpr int LDS_SHORTS = 32768;                 // 65536 B -> hard cap 2 blocks/CU

typedef __attribute__((ext_vector_type(8)))  short short8;
typedef __attribute__((ext_vector_type(16))) float f32x16;

struct T3 { int a, b, c; };   // sorted ascending; 18 = unused factor; 19 = pad

constexpr int rho1(int v) {
    if (v < 16)  return (v & ~3) | ((v + 1) & 3);
    if (v == 16) return 17;
    if (v == 17) return 16;
    return v;
}
constexpr int rho2v(int v) { return rho1(rho1(v)); }

constexpr T3 sort3(int u0, int u1, int u2) {
    int t = 0;
    if (u0 > u1) { t = u0; u0 = u1; u1 = t; }
    if (u1 > u2) { t = u1; u1 = u2; u2 = t; }
    if (u0 > u1) { t = u0; u0 = u1; u1 = t; }
    return T3{u0, u1, u2};
}
constexpr T3 rho3(T3 t) { return sort3(rho1(t.a), rho1(t.b), rho1(t.c)); }

constexpr bool t3_less(T3 x, T3 y) {
    if (x.a != y.a) return x.a < y.a;
    if (x.b != y.b) return x.b < y.b;
    return x.c < y.c;
}
constexpr bool t3_eq(T3 x, T3 y) { return x.a == y.a && x.b == y.b && x.c == y.c; }

constexpr int rank_of(T3 t) {
    int deg = (t.a < 18) + (t.b < 18) + (t.c < 18);
    if (deg == 0) return 0;
    if (deg == 1) return 1 + t.a;
    if (deg == 2) {
        int r = 19;
        for (int a = 0; a < t.a; ++a) r += 18 - a;
        return r + (t.b - t.a);
    }
    int r = 190;
    for (int a = 0; a < t.a; ++a) { int n = 18 - a; r += n * (n + 1) / 2; }
    for (int b = t.a; b < t.b; ++b) r += 18 - b;
    return r + (t.c - t.b);
}

struct RepTables {
    signed char va[NSLOTS], vb[NSLOTS], vc[NSLOTS];
    short p[4][NSLOTS];   // flat term index for group g's k-position; -1 => zero W
    int count;
};

constexpr void consider(RepTables& R, int& s, T3 t) {
    T3 im[4] = {t, T3{0, 0, 0}, T3{0, 0, 0}, T3{0, 0, 0}};
    im[1] = rho3(im[0]);
    im[2] = rho3(im[1]);
    im[3] = rho3(im[2]);
    for (int g = 1; g < 4; ++g)
        if (t3_less(im[g], t)) return;   // not the orbit representative
    R.va[s] = (signed char)t.a; R.vb[s] = (signed char)t.b; R.vc[s] = (signed char)t.c;
    for (int g = 0; g < 4; ++g) {
        bool dup = false;
        for (int h = 0; h < g; ++h)
            if (t3_eq(im[h], im[g])) dup = true;
        R.p[g][s] = dup ? (short)-1 : (short)rank_of(im[g]);
    }
    ++s;
}

constexpr RepTables make_tables() {
    RepTables R{};
    int s = 0;
    consider(R, s, T3{18, 18, 18});
    for (int a = 0; a < NVARS; ++a) consider(R, s, T3{a, 18, 18});
    for (int a = 0; a < NVARS; ++a)
        for (int b = a; b < NVARS; ++b) consider(R, s, T3{a, b, 18});
    for (int a = 0; a < NVARS; ++a)
        for (int b = a; b < NVARS; ++b)
            for (int c = b; c < NVARS; ++c) consider(R, s, T3{a, b, c});
    R.count = s;
    for (; s < NSLOTS; ++s) {
        R.va[s] = 19; R.vb[s] = 19; R.vc[s] = 19;
        for (int g = 0; g < 4; ++g) R.p[g][s] = -1;
    }
    return R;
}

constexpr RepTables h_tab = make_tables();          // compile-time use
static_assert(h_tab.count == 342, "orbit enumeration must give 342 rep slots");
__device__ const RepTables d_tab = make_tables();   // runtime use (prep)

// Module-scope staging buffer for the prepped W table (NOT harness workspace).
__device__ __align__(16) short g_wf2[WF2_SHORTS];

// ---- bf16 pair pack --------------------------------------------------------

#if __has_builtin(__builtin_amdgcn_cvt_pk_bf16_f32)
typedef __bf16 bf16x2 __attribute__((ext_vector_type(2)));
__device__ __forceinline__ unsigned pack2(float f0, float f1) {
    bf16x2 r = __builtin_amdgcn_cvt_pk_bf16_f32(f0, f1);   // lo=f0, hi=f1, RNE
    return __builtin_bit_cast(unsigned, r);
}
#else
__device__ __forceinline__ unsigned pack2(float f0, float f1) {
    unsigned u0 = __float_as_uint(f0) + 0x8000u;
    unsigned u1 = __float_as_uint(f1) + 0x8000u;
    return __builtin_amdgcn_perm(u1, u0, 0x07060302u);     // lo=bf16(f0), hi=bf16(f1)
}
#endif

// ---- main kernel -----------------------------------------------------------

template <int S>
__device__ __forceinline__ float term_val(const float (&x)[NVARS]) {
    constexpr int a = h_tab.va[S], b = h_tab.vb[S], c = h_tab.vc[S];
    if constexpr (a >= 19)      return 0.0f;                 // pad slot
    else if constexpr (a == 18) return 1.0f;                 // constant
    else if constexpr (b == 18) return x[a];
    else if constexpr (c == 18) return x[a] * x[b];
    else                        return x[a] * x[b] * x[c];
}

union AFrag { unsigned u[4]; short8 v; };

// Fused eval+pack: keeps only 2 term floats live at a time.
template <int S, int... J>
__device__ __forceinline__ void pack8(const float (&x)[NVARS], AFrag& af,
                                      std::integer_sequence<int, J...>) {
    ((af.u[J] = pack2(term_val<S + 2 * J>(x), term_val<S + 2 * J + 1>(x))), ...);
}

template <int CI>
__device__ __forceinline__ void kstep32(const float (&x)[NVARS],
                                        const short* pB, f32x16& acc) {
    constexpr int S = (CI < 43 ? CI : CI - 43) * 8;   // slot base for this chunk
    AFrag af;
    pack8<S>(x, af, std::make_integer_sequence<int, 4>{});
    short8 b = *(const short8*)(pB + CI * CH_STRIDE);   // ds_read_b128
    acc = __builtin_amdgcn_mfma_f32_32x32x16_bf16(af.v, b, acc, 0, 0, 0);
}

template <int BASE, int... CI>
__device__ __forceinline__ void kloop32(const float (&x)[NVARS],
                                        const short* pB, f32x16& acc,
                                        std::integer_sequence<int, CI...>) {
    (kstep32<BASE + CI>(x, pB, acc), ...);
}

__device__ __forceinline__ void load_x(const float* __restrict__ z,
                                       const float* __restrict__ betas,
                                       int arow, bool s1, float (&x)[NVARS]) {
    float x0[NVARS];
    const float4* z4 = (const float4*)(z + (size_t)arow * 16);
    float4 v0 = z4[0], v1 = z4[1], v2 = z4[2], v3 = z4[3];
    x0[0]  = v0.x; x0[1]  = v0.y; x0[2]  = v0.z; x0[3]  = v0.w;
    x0[4]  = v1.x; x0[5]  = v1.y; x0[6]  = v1.z; x0[7]  = v1.w;
    x0[8]  = v2.x; x0[9]  = v2.y; x0[10] = v2.z; x0[11] = v2.w;
    x0[12] = v3.x; x0[13] = v3.y; x0[14] = v3.z; x0[15] = v3.w;
    const float2 b2 = *(const float2*)(betas + (size_t)arow * 2);
    x0[16] = b2.x; x0[17] = b2.y;
#pragma unroll
    for (int v = 0; v < NVARS; ++v) x[v] = s1 ? x0[rho1(v)] : x0[v];
}

__global__ __launch_bounds__(512, 4) void vindy_mfma(const float* __restrict__ z,
                                                     const float* __restrict__ betas,
                                                     float* __restrict__ out) {
    __shared__ __align__(16) short ldsW[LDS_SHORTS];   // 64 KiB -> hard 2 blocks/CU

    // stage all W fragments once per block (flat 16B copies, fully coalesced)
    {
        const float4* src = (const float4*)g_wf2;
        float4* dst = (float4*)ldsW;
        for (int i = threadIdx.x; i < WF2_SHORTS / 8; i += 512) dst[i] = src[i];
    }
    __syncthreads();

    const int lane = threadIdx.x & 63;
    const int wave = threadIdx.x >> 6;   // 0..7
    const int h    = lane >> 5;          // K-half -> rho-power h (phase 1), h+2 (phase 2)
    const int col  = lane & 31;          // A row within tile; C col
    const int row0 = blockIdx.x * 256 + wave * 32;

    // x permuted by rho^h for phase 1
    float x1[NVARS];
    load_x(z, betas, row0 + col, h != 0, x1);

    const int col_eff = (col < NOUT) ? col : NOUT;   // col 18 = zero slot
    const short* pB = ldsW + h * 152 + col_eff * 8;

    f32x16 acc;
#pragma unroll
    for (int i = 0; i < 16; ++i) acc[i] = 0.0f;

    // phase 1: chunks 0..42, g = h
    kloop32<0>(x1, pB, acc, std::make_integer_sequence<int, 43>{});

    // phase switch: rho^2 renaming (compile-time register permutation, free)
    float x2[NVARS];
#pragma unroll
    for (int v = 0; v < NVARS; ++v) x2[v] = x1[rho2v(v)];

    // phase 2: chunks 43..85, g = h + 2
    kloop32<43>(x2, pB, acc, std::make_integer_sequence<int, 43>{});

    // C/D 32x32 layout: col = lane&31, row = (reg&3) + 8*(reg>>2) + 4*h
    if (col < NOUT) {
#pragma unroll
        for (int q = 0; q < 4; ++q) {
#pragma unroll
            for (int r = 0; r < 4; ++r) {
                int row = r + 8 * q + 4 * h;
                out[(size_t)(row0 + row) * NOUT + col] = acc[q * 4 + r];
            }
        }
    }
}

// ---- prep: W fragments in staged layout ------------------------------------
// g_wf2[c*304 + h*152 + col*8 + j]:
//   col < 18:  W[p[g][s]][col],  g = (c<43 ? h : 2+h),  s = (c<43 ? c : c-43)*8+j
//   col == 18: zero slot (read broadcast by lanes col>=18)

__global__ void prep_wfrag(const float* __restrict__ xi, const float* __restrict__ mask) {
    int i = blockIdx.x * blockDim.x + threadIdx.x;
    if (i >= WF2_SHORTS) return;
    int c  = i / CH_STRIDE;
    int r  = i - c * CH_STRIDE;
    int h  = r / 152;
    int r2 = r - h * 152;
    int col = r2 >> 3, j = r2 & 7;
    float v = 0.0f;
    if (col < NOUT) {
        int g = (c < 43 ? 0 : 2) + h;
        int s = (c < 43 ? c : c - 43) * 8 + j;
        int p = d_tab.p[g][s];
        if (p >= 0) v = xi[p * NOUT + col] * mask[p * NOUT + col];
    }
    g_wf2[i] = __builtin_bit_cast(short, __float2bfloat16(v));
}

extern "C" void kernel_launch(void* const* d_in, const int* in_sizes, int n_in,
                              void* d_out, int out_size, void* d_ws, size_t ws_size,
                              hipStream_t stream) {
    const float* z     = (const float*)d_in[0];
    const float* betas = (const float*)d_in[1];
    const float* xi    = (const float*)d_in[2];
    const float* mask  = (const float*)d_in[3];
    float* out = (float*)d_out;
    (void)d_ws; (void)ws_size;   // workspace unused (poison fill is unconditional anyway)

    prep_wfrag<<<(WF2_SHORTS + 255) / 256, 256, 0, stream>>>(xi, mask);
    vindy_mfma<<<NROWS / 256, 512, 0, stream>>>(z, betas, out);
}